// Round 2
// 154.595 us; speedup vs baseline: 1.1014x; 1.1014x over previous
//
#include <hip/hip_runtime.h>

// Tile: 16 output rows x 64 output cols; 4 tiles per (n,c); grid 16384.
// Stages: S0 load -> S1 V-up(x2) -> S2 [H-up + act + H-down] fused -> S4 V-down + store.
//   s_in[26 x 80] : input rows gy0-5..gy0+20, cols -5..74 zero-padded   (bufA)
//   t1  [42 x 80] : vertical x2 up, cols 0..73 valid                    (bufB)
//   t3  [42 x 72] : H-up+act+H-down result, cols 0..63 valid            (bufA, s_in dead)
// LDS = (3024 + 3376 + 24)*4 ~= 25.7 KB -> 6 blocks/CU (LDS-limited).
// R1: S1 rebalanced 111->222 threads (1 col/thread), S4 128->256 threads
//     (1 col/thread), S0 float4 global loads. S2 unchanged.
// R2: identical resubmit (R1 bench died on container infra, no data).
#define SIN 80
#define ST1 80
#define ST3 72

__global__ __launch_bounds__(256, 5)
void synth_fused(const float* __restrict__ x, const float* __restrict__ bias,
                 const float* __restrict__ fu, const float* __restrict__ fd,
                 float* __restrict__ out)
{
    __shared__ __align__(16) float bufA[3024];
    __shared__ __align__(16) float bufB[3376];   // t1 42x80 + slack (q=5 reads to +21)
    __shared__ float sfilt[24];
    float* const s_in = bufA;
    float* const s_t3 = bufA;
    float* const s_t1 = bufB;

    const int tid  = threadIdx.x;
    const int bx   = blockIdx.x;
    const int tile = bx & 3;
    const int nc   = bx >> 2;
    const int gy0  = tile << 4;

    if (tid < 24) sfilt[tid] = (tid < 12) ? fu[tid] : fd[tid - 12];
    const float bc = bias[nc & 511];
    const float* __restrict__ xc = x + ((size_t)nc << 12);

    // ---- S0: load 26 rows x 64 cols (float4, coalesced) + zero pad cols ----
    #pragma unroll
    for (int it = 0; it < 2; ++it) {
        int idx = tid + it * 256;
        if (idx < 416) {                         // 26 rows * 16 float4
            int r  = idx >> 4;
            int c4 = (idx & 15) << 2;
            int gy = gy0 - 5 + r;
            float4 v = make_float4(0.f, 0.f, 0.f, 0.f);
            if ((unsigned)gy < 64u)
                v = *reinterpret_cast<const float4*>(xc + (gy << 6) + c4);
            float* dst = s_in + r * SIN + 5 + c4;
            dst[0] = v.x; dst[1] = v.y; dst[2] = v.z; dst[3] = v.w;
        }
    }
    #pragma unroll
    for (int it = 0; it < 2; ++it) {                 // 26*16 pad slots (cols 0..4, 69..79)
        int idx = tid + it * 256;
        if (idx < 416) {
            int r  = idx >> 4;
            int pc = idx & 15;
            int c  = (pc < 5) ? pc : (64 + pc);
            s_in[r * SIN + c] = 0.0f;
        }
    }
    __syncthreads();

    float u[12], g[12];
    #pragma unroll
    for (int k = 0; k < 12; ++k) u[k] = sfilt[k];
    #pragma unroll
    for (int k = 0; k < 12; ++k) g[k] = sfilt[23 - k];   // g[k] = fd[11-k]

    // ---- S1: vertical x2 up, 1 col/thread. 222 threads (g3 0..2, c 0..73) ----
    // t1[2m][c]   = sum_j u[10-2j] * s_in[m+j][c]
    // t1[2m+1][c] = sum_j u[11-2j] * s_in[m+j][c],  m = 7*g3 + mm, mm 0..6
    if (tid < 222) {
        const int g3 = tid / 74;
        const int c  = tid - 74 * g3;
        const float* ip = s_in + (7 * g3) * SIN + c;
        float rv[12];
        #pragma unroll
        for (int j = 0; j < 12; ++j) rv[j] = ip[j * SIN];
        float* op = s_t1 + (14 * g3) * ST1 + c;
        #pragma unroll
        for (int m = 0; m < 7; ++m) {
            float aE = u[10]*rv[m];
            aE = fmaf(u[8], rv[m+1], aE); aE = fmaf(u[6], rv[m+2], aE);
            aE = fmaf(u[4], rv[m+3], aE); aE = fmaf(u[2], rv[m+4], aE);
            aE = fmaf(u[0], rv[m+5], aE);
            float aO = u[11]*rv[m];
            aO = fmaf(u[9], rv[m+1], aO); aO = fmaf(u[7], rv[m+2], aO);
            aO = fmaf(u[5], rv[m+3], aO); aO = fmaf(u[3], rv[m+4], aO);
            aO = fmaf(u[1], rv[m+5], aO);
            op[(2*m) * ST1]     = aE;
            op[(2*m + 1) * ST1] = aO;
        }
    }
    __syncthreads();

    // fold the x4 up-gain into the up taps (only H-stage applies gain, once)
    #pragma unroll
    for (int k = 0; k < 12; ++k) u[k] *= 4.0f;

    // ---- S2: fused H-up + bias/lrelu*sqrt2/clamp + H-down. 252 threads (r 0..41, q 0..5) ----
    // t2[m] = act( sum_j u[10+(m&1)-2j]*t1[r][12q+(m>>1)+j] + bc ),  m 0..33
    // t3[r][12q+i] = sum_k g[k]*t2[2i+k],  i 0..11
    // q=5: t1 cols >=74 garbage -> only feeds m>=18 -> only t3 cols >=64 (pad).
    if (tid < 252) {
        const int r = tid / 6;
        const int q = tid - 6 * r;
        const float* t1r = s_t1 + r * ST1 + 12 * q;
        float w[22];
        #pragma unroll
        for (int j = 0; j < 5; ++j) {
            float4 v4 = *reinterpret_cast<const float4*>(t1r + 4 * j);
            w[4*j] = v4.x; w[4*j+1] = v4.y; w[4*j+2] = v4.z; w[4*j+3] = v4.w;
        }
        { float2 v2 = *reinterpret_cast<const float2*>(t1r + 20); w[20] = v2.x; w[21] = v2.y; }
        const float P = 0.84852813742385703f;   // 0.6*sqrt2
        const float Q = 0.56568542494923802f;   // 0.4*sqrt2
        float t2v[34];
        #pragma unroll
        for (int i = 0; i < 17; ++i) {
            float zE = fmaf(u[10], w[i], bc);
            zE = fmaf(u[8], w[i+1], zE); zE = fmaf(u[6], w[i+2], zE);
            zE = fmaf(u[4], w[i+3], zE); zE = fmaf(u[2], w[i+4], zE);
            zE = fmaf(u[0], w[i+5], zE);
            float zO = fmaf(u[11], w[i], bc);
            zO = fmaf(u[9], w[i+1], zO); zO = fmaf(u[7], w[i+2], zO);
            zO = fmaf(u[5], w[i+3], zO); zO = fmaf(u[3], w[i+4], zO);
            zO = fmaf(u[1], w[i+5], zO);
            float vE = fmaf(Q, __builtin_fabsf(zE), P * zE);
            float vO = fmaf(Q, __builtin_fabsf(zO), P * zO);
            t2v[2*i]   = __builtin_amdgcn_fmed3f(vE, -256.0f, 256.0f);
            t2v[2*i+1] = __builtin_amdgcn_fmed3f(vO, -256.0f, 256.0f);
        }
        float* t3r = s_t3 + r * ST3 + 12 * q;
        #pragma unroll
        for (int i = 0; i < 3; ++i) {
            float4 o4;
            float* op = &o4.x;
            #pragma unroll
            for (int s = 0; s < 4; ++s) {
                const int oi = 4 * i + s;
                float acc = g[0] * t2v[2*oi];
                #pragma unroll
                for (int k = 1; k < 12; ++k) acc = fmaf(g[k], t2v[2*oi + k], acc);
                op[s] = acc;
            }
            *reinterpret_cast<float4*>(t3r + 4 * i) = o4;
        }
    }
    __syncthreads();

    // ---- S4: vertical /2 down, 1 col/thread, 256 threads (rc 0..3, c 0..63) ----
    // out rows gy0+4rc..gy0+4rc+3, reads t3 rows 8rc..8rc+17 at col c
    {
        const int c  = tid & 63;
        const int rc = tid >> 6;
        const float* t3c = s_t3 + (rc << 3) * ST3 + c;
        float wv[18];
        #pragma unroll
        for (int j = 0; j < 18; ++j) wv[j] = t3c[j * ST3];
        float* op = out + ((size_t)nc << 12) + ((size_t)(gy0 + (rc << 2)) << 6) + c;
        #pragma unroll
        for (int i = 0; i < 4; ++i) {
            float acc = g[0] * wv[2*i];
            #pragma unroll
            for (int k = 1; k < 12; ++k) acc = fmaf(g[k], wv[2*i + k], acc);
            op[(size_t)(i << 6)] = acc;
        }
    }
}

extern "C" void kernel_launch(void* const* d_in, const int* in_sizes, int n_in,
                              void* d_out, int out_size, void* d_ws, size_t ws_size,
                              hipStream_t stream) {
    const float* x    = (const float*)d_in[0];
    const float* bias = (const float*)d_in[1];
    const float* fu   = (const float*)d_in[2];
    const float* fd   = (const float*)d_in[3];
    float* out        = (float*)d_out;

    dim3 grid(8 * 512 * 4);   // (n*c) x 4 row-tiles of 16x64
    dim3 block(256);
    hipLaunchKernelGGL(synth_fused, grid, block, 0, stream, x, bias, fu, fd, out);
}